// Round 1
// baseline (489.019 us; speedup 1.0000x reference)
//
#include <hip/hip_runtime.h>

#define DIM 64

__device__ __forceinline__ float rdlane(float v, int l) {
    return __int_as_float(__builtin_amdgcn_readlane(__float_as_int(v), l));
}

// MODE: 0 = plain (out = in@W^T + b)
//       1 = residual (out = (1+eps)*resid + in@W^T + b)
//       2 = relu (out = max(in@W^T + b, 0))
template <int MODE>
__global__ __launch_bounds__(256) void gemm64_kernel(
    const float* __restrict__ in, const float* __restrict__ W,
    const float* __restrict__ bias, const float* __restrict__ resid,
    const float* __restrict__ eps, float* __restrict__ out, int nrows)
{
    const int lane  = threadIdx.x & 63;
    const int wid   = blockIdx.x * (blockDim.x >> 6) + (threadIdx.x >> 6);
    const int nwav  = gridDim.x * (blockDim.x >> 6);

    // lane l holds W[l][0..63] (row l of [OUT][IN] weight) in VGPRs
    float wreg[DIM];
#pragma unroll
    for (int j4 = 0; j4 < DIM / 4; ++j4) {
        const float4 w = *reinterpret_cast<const float4*>(W + lane * DIM + j4 * 4);
        wreg[4 * j4 + 0] = w.x; wreg[4 * j4 + 1] = w.y;
        wreg[4 * j4 + 2] = w.z; wreg[4 * j4 + 3] = w.w;
    }
    const float b = bias[lane];
    float escale = 0.f;
    if constexpr (MODE == 1) escale = 1.0f + eps[0];

    int r = wid;
    if (r >= nrows) return;
    float vx = in[(size_t)r * DIM + lane];
    float vh = 0.f;
    if constexpr (MODE == 1) vh = resid[(size_t)r * DIM + lane];

    while (r < nrows) {
        const int rn = r + nwav;
        float vxn = 0.f, vhn = 0.f;
        if (rn < nrows) {
            vxn = in[(size_t)rn * DIM + lane];
            if constexpr (MODE == 1) vhn = resid[(size_t)rn * DIM + lane];
        }
        float a0 = 0.f, a1 = 0.f, a2 = 0.f, a3 = 0.f;
#pragma unroll
        for (int j = 0; j < DIM; j += 4) {
            a0 = fmaf(wreg[j + 0], rdlane(vx, j + 0), a0);
            a1 = fmaf(wreg[j + 1], rdlane(vx, j + 1), a1);
            a2 = fmaf(wreg[j + 2], rdlane(vx, j + 2), a2);
            a3 = fmaf(wreg[j + 3], rdlane(vx, j + 3), a3);
        }
        float s = (a0 + a1) + (a2 + a3) + b;
        if constexpr (MODE == 1) s = fmaf(escale, vh, s);
        if constexpr (MODE == 2) s = fmaxf(s, 0.f);
        out[(size_t)r * DIM + lane] = s;
        vx = vxn; vh = vhn;
        r = rn;
    }
}

__global__ void zero_kernel(int* __restrict__ p, int n) {
    int i = blockIdx.x * blockDim.x + threadIdx.x;
    if (i < n) p[i] = 0;
}

__global__ void hist_kernel(const int* __restrict__ rows, int* __restrict__ counts, int E) {
    int i = blockIdx.x * blockDim.x + threadIdx.x;
    if (i < E) atomicAdd(&counts[rows[i]], 1);
}

__device__ __forceinline__ int wave_incl_scan(int v, int lane) {
#pragma unroll
    for (int off = 1; off < 64; off <<= 1) {
        int t = __shfl_up(v, (unsigned)off, 64);
        if (lane >= off) v += t;
    }
    return v;
}

__global__ __launch_bounds__(256) void scan1_kernel(
    const int* __restrict__ counts, int* __restrict__ partial,
    int* __restrict__ blocksums, int n)
{
    const int tid = threadIdx.x, lane = tid & 63, wid = tid >> 6;
    const int i = blockIdx.x * 256 + tid;
    int v = (i < n) ? counts[i] : 0;
    int inc = wave_incl_scan(v, lane);
    __shared__ int wtot[4];
    if (lane == 63) wtot[wid] = inc;
    __syncthreads();
    int wexcl = 0;
#pragma unroll
    for (int w = 0; w < 4; ++w)
        if (w < wid) wexcl += wtot[w];
    if (i < n) partial[i] = wexcl + inc - v;  // block-local exclusive
    if (tid == 255) blocksums[blockIdx.x] = wexcl + inc;
}

__global__ __launch_bounds__(512) void scan2_kernel(int* __restrict__ bs, int nb) {
    const int tid = threadIdx.x, lane = tid & 63, wid = tid >> 6;
    int v = (tid < nb) ? bs[tid] : 0;
    int inc = wave_incl_scan(v, lane);
    __shared__ int wtot[8];
    if (lane == 63) wtot[wid] = inc;
    __syncthreads();
    int wexcl = 0;
#pragma unroll
    for (int w = 0; w < 8; ++w)
        if (w < wid) wexcl += wtot[w];
    if (tid < nb) bs[tid] = wexcl + inc - v;  // exclusive, in place
}

__global__ __launch_bounds__(256) void scan3_kernel(
    int* __restrict__ offsets, const int* __restrict__ bs,
    int* __restrict__ cursor, int n, int E)
{
    const int i = blockIdx.x * 256 + threadIdx.x;
    if (i < n) {
        const int v = offsets[i] + bs[i >> 8];
        offsets[i] = v;
        cursor[i] = v;
    }
    if (i == 0) offsets[n] = E;
}

__global__ void scatter_kernel(const int* __restrict__ ei, const int* __restrict__ sgn,
                               int* __restrict__ cursor, int* __restrict__ edata, int E) {
    const int i = blockIdx.x * blockDim.x + threadIdx.x;
    if (i < E) {
        const int r = ei[i];
        const int c = ei[E + i];
        const int s = sgn[i];
        const int pos = atomicAdd(&cursor[r], 1);
        edata[pos] = c | (s << 20);
    }
}

// one wave per node; lane = feature dim (head = lane>>4, hd = lane&15)
__global__ __launch_bounds__(256) void attn_kernel(
    const float* __restrict__ h, const int* __restrict__ offsets,
    const int* __restrict__ edata, const float* __restrict__ sign_tab,
    float* __restrict__ aggr, int n)
{
    const int lane = threadIdx.x & 63;
    const int node = blockIdx.x * 4 + (threadIdx.x >> 6);
    if (node >= n) return;
    const float st0 = sign_tab[lane & 15];
    const float st1 = sign_tab[16 + (lane & 15)];
    const float hi = h[(size_t)node * DIM + lane];
    const int beg = offsets[node], end = offsets[node + 1];
    float den = 0.f, msg = 0.f;
    for (int e = beg; e < end; ++e) {
        const int p = edata[e];                 // wave-uniform
        const int col = p & 0xFFFFF;
        const float se = (p >> 20) ? st1 : st0;
        const float hj = h[(size_t)col * DIM + lane];
        float sc = hi * hj * se;
        sc += __shfl_xor(sc, 1, 64);
        sc += __shfl_xor(sc, 2, 64);
        sc += __shfl_xor(sc, 4, 64);
        sc += __shfl_xor(sc, 8, 64);            // 16-lane (per-head) sum
        const float ex = __expf(sc);
        den += ex;
        msg = fmaf(ex, hj, msg);
    }
    aggr[(size_t)node * DIM + lane] = msg / (den + 1e-16f);
}

extern "C" void kernel_launch(void* const* d_in, const int* in_sizes, int n_in,
                              void* d_out, int out_size, void* d_ws, size_t ws_size,
                              hipStream_t stream) {
    const float* x        = (const float*)d_in[0];
    const int*   ei       = (const int*)d_in[1];   // [2,E] flattened
    const int*   esign    = (const int*)d_in[2];
    const float* Wl_w     = (const float*)d_in[3];
    const float* Wl_b     = (const float*)d_in[4];
    const float* sign_tab = (const float*)d_in[5];
    const float* Wh_w     = (const float*)d_in[6];
    const float* Wh_b     = (const float*)d_in[7];
    const float* w1       = (const float*)d_in[8];
    const float* b1       = (const float*)d_in[9];
    const float* w2       = (const float*)d_in[10];
    const float* b2       = (const float*)d_in[11];
    const float* eps      = (const float*)d_in[12];
    float* out = (float*)d_out;

    const int N = in_sizes[0] / DIM;
    const int E = in_sizes[2];

    float* h      = (float*)d_ws;
    float* aggr   = h + (size_t)N * DIM;
    int*   counts = (int*)(aggr + (size_t)N * DIM);
    int*   offs   = counts + N;
    int*   cursor = offs + (N + 1);
    int*   bsums  = cursor + N;
    int*   edata  = bsums + 1024;

    const int GB = 1536;  // gemm blocks (6144 waves)
    const int nb = (N + 255) / 256;

    // h = x @ Wl^T + Wl_b
    gemm64_kernel<0><<<GB, 256, 0, stream>>>(x, Wl_w, Wl_b, nullptr, nullptr, h, N);

    // CSR build
    zero_kernel<<<(N + 255) / 256, 256, 0, stream>>>(counts, N);
    hist_kernel<<<(E + 255) / 256, 256, 0, stream>>>(ei, counts, E);
    scan1_kernel<<<nb, 256, 0, stream>>>(counts, offs, bsums, N);
    scan2_kernel<<<1, 512, 0, stream>>>(bsums, nb);
    scan3_kernel<<<nb, 256, 0, stream>>>(offs, bsums, cursor, N, E);
    scatter_kernel<<<(E + 255) / 256, 256, 0, stream>>>(ei, esign, cursor, edata, E);

    // segment softmax + aggregation (one wave per node)
    attn_kernel<<<(N + 3) / 4, 256, 0, stream>>>(h, offs, edata, sign_tab, aggr, N);

    // z = (1+eps)*h + aggr @ Wh^T + Wh_b   (in place into aggr)
    gemm64_kernel<1><<<GB, 256, 0, stream>>>(aggr, Wh_w, Wh_b, h, eps, aggr, N);
    // hid = relu(z @ w1^T + b1)            (in place)
    gemm64_kernel<2><<<GB, 256, 0, stream>>>(aggr, w1, b1, nullptr, nullptr, aggr, N);
    // out = hid @ w2^T + b2
    gemm64_kernel<0><<<GB, 256, 0, stream>>>(aggr, w2, b2, nullptr, nullptr, out, N);
}

// Round 2
// 354.369 us; speedup vs baseline: 1.3800x; 1.3800x over previous
//
#include <hip/hip_runtime.h>

#define DIM 64

__device__ __forceinline__ float rdlane(float v, int l) {
    return __int_as_float(__builtin_amdgcn_readlane(__float_as_int(v), l));
}

template <int CTRL>
__device__ __forceinline__ float qperm(float v) {
    return __int_as_float(__builtin_amdgcn_update_dpp(
        0, __float_as_int(v), CTRL, 0xF, 0xF, true));
}

// MODE 0: out = in@W^T + b
template <int MODE>
__global__ __launch_bounds__(256) void gemm64_kernel(
    const float* __restrict__ in, const float* __restrict__ W,
    const float* __restrict__ bias, float* __restrict__ out, int nrows)
{
    const int lane  = threadIdx.x & 63;
    const int wid   = blockIdx.x * (blockDim.x >> 6) + (threadIdx.x >> 6);
    const int nwav  = gridDim.x * (blockDim.x >> 6);

    float wreg[DIM];
#pragma unroll
    for (int j4 = 0; j4 < DIM / 4; ++j4) {
        const float4 w = *reinterpret_cast<const float4*>(W + lane * DIM + j4 * 4);
        wreg[4 * j4 + 0] = w.x; wreg[4 * j4 + 1] = w.y;
        wreg[4 * j4 + 2] = w.z; wreg[4 * j4 + 3] = w.w;
    }
    const float b = bias[lane];

    int r = wid;
    if (r >= nrows) return;
    float vx = in[(size_t)r * DIM + lane];

    while (r < nrows) {
        const int rn = r + nwav;
        float vxn = 0.f;
        if (rn < nrows) vxn = in[(size_t)rn * DIM + lane];
        float a0 = 0.f, a1 = 0.f, a2 = 0.f, a3 = 0.f;
#pragma unroll
        for (int j = 0; j < DIM; j += 4) {
            a0 = fmaf(wreg[j + 0], rdlane(vx, j + 0), a0);
            a1 = fmaf(wreg[j + 1], rdlane(vx, j + 1), a1);
            a2 = fmaf(wreg[j + 2], rdlane(vx, j + 2), a2);
            a3 = fmaf(wreg[j + 3], rdlane(vx, j + 3), a3);
        }
        out[(size_t)r * DIM + lane] = (a0 + a1) + (a2 + a3) + b;
        vx = vxn;
        r = rn;
    }
}

// fused tail: z = (1+eps)*h + aggr@Wh^T+bh ; hid = relu(z@W1^T+b1) ; out = hid@W2^T+b2
__global__ __launch_bounds__(256, 2) void tail_kernel(
    const float* __restrict__ aggr, const float* __restrict__ h,
    const float* __restrict__ Wh, const float* __restrict__ bh,
    const float* __restrict__ W1, const float* __restrict__ b1,
    const float* __restrict__ W2, const float* __restrict__ b2,
    const float* __restrict__ eps, float* __restrict__ out, int nrows)
{
    const int lane  = threadIdx.x & 63;
    const int wid   = blockIdx.x * (blockDim.x >> 6) + (threadIdx.x >> 6);
    const int nwav  = gridDim.x * (blockDim.x >> 6);

    float wh[DIM], wa[DIM], wb[DIM];
#pragma unroll
    for (int j4 = 0; j4 < DIM / 4; ++j4) {
        float4 t;
        t = *reinterpret_cast<const float4*>(Wh + lane * DIM + j4 * 4);
        wh[4*j4+0]=t.x; wh[4*j4+1]=t.y; wh[4*j4+2]=t.z; wh[4*j4+3]=t.w;
        t = *reinterpret_cast<const float4*>(W1 + lane * DIM + j4 * 4);
        wa[4*j4+0]=t.x; wa[4*j4+1]=t.y; wa[4*j4+2]=t.z; wa[4*j4+3]=t.w;
        t = *reinterpret_cast<const float4*>(W2 + lane * DIM + j4 * 4);
        wb[4*j4+0]=t.x; wb[4*j4+1]=t.y; wb[4*j4+2]=t.z; wb[4*j4+3]=t.w;
    }
    const float bhv = bh[lane], b1v = b1[lane], b2v = b2[lane];
    const float escale = 1.0f + eps[0];

    int r = wid;
    if (r >= nrows) return;
    float va = aggr[(size_t)r * DIM + lane];
    float vh = h[(size_t)r * DIM + lane];

    while (r < nrows) {
        const int rn = r + nwav;
        float van = 0.f, vhn = 0.f;
        if (rn < nrows) {
            van = aggr[(size_t)rn * DIM + lane];
            vhn = h[(size_t)rn * DIM + lane];
        }
        float a0 = 0.f, a1 = 0.f, a2 = 0.f, a3 = 0.f;
#pragma unroll
        for (int j = 0; j < DIM; j += 4) {
            a0 = fmaf(wh[j + 0], rdlane(va, j + 0), a0);
            a1 = fmaf(wh[j + 1], rdlane(va, j + 1), a1);
            a2 = fmaf(wh[j + 2], rdlane(va, j + 2), a2);
            a3 = fmaf(wh[j + 3], rdlane(va, j + 3), a3);
        }
        float z = (a0 + a1) + (a2 + a3) + bhv;
        z = fmaf(escale, vh, z);

        a0 = a1 = a2 = a3 = 0.f;
#pragma unroll
        for (int j = 0; j < DIM; j += 4) {
            a0 = fmaf(wa[j + 0], rdlane(z, j + 0), a0);
            a1 = fmaf(wa[j + 1], rdlane(z, j + 1), a1);
            a2 = fmaf(wa[j + 2], rdlane(z, j + 2), a2);
            a3 = fmaf(wa[j + 3], rdlane(z, j + 3), a3);
        }
        const float hid = fmaxf((a0 + a1) + (a2 + a3) + b1v, 0.f);

        a0 = a1 = a2 = a3 = 0.f;
#pragma unroll
        for (int j = 0; j < DIM; j += 4) {
            a0 = fmaf(wb[j + 0], rdlane(hid, j + 0), a0);
            a1 = fmaf(wb[j + 1], rdlane(hid, j + 1), a1);
            a2 = fmaf(wb[j + 2], rdlane(hid, j + 2), a2);
            a3 = fmaf(wb[j + 3], rdlane(hid, j + 3), a3);
        }
        out[(size_t)r * DIM + lane] = (a0 + a1) + (a2 + a3) + b2v;

        va = van; vh = vhn;
        r = rn;
    }
}

__global__ void zero_kernel(int* __restrict__ p, int n) {
    int i = blockIdx.x * blockDim.x + threadIdx.x;
    if (i < n) p[i] = 0;
}

__global__ void hist_kernel(const int* __restrict__ rows, int* __restrict__ counts, int E) {
    int i = blockIdx.x * blockDim.x + threadIdx.x;
    if (i < E) atomicAdd(&counts[rows[i]], 1);
}

__device__ __forceinline__ int wave_incl_scan(int v, int lane) {
#pragma unroll
    for (int off = 1; off < 64; off <<= 1) {
        int t = __shfl_up(v, (unsigned)off, 64);
        if (lane >= off) v += t;
    }
    return v;
}

__global__ __launch_bounds__(256) void scan1_kernel(
    const int* __restrict__ counts, int* __restrict__ partial,
    int* __restrict__ blocksums, int n)
{
    const int tid = threadIdx.x, lane = tid & 63, wid = tid >> 6;
    const int i = blockIdx.x * 256 + tid;
    int v = (i < n) ? counts[i] : 0;
    int inc = wave_incl_scan(v, lane);
    __shared__ int wtot[4];
    if (lane == 63) wtot[wid] = inc;
    __syncthreads();
    int wexcl = 0;
#pragma unroll
    for (int w = 0; w < 4; ++w)
        if (w < wid) wexcl += wtot[w];
    if (i < n) partial[i] = wexcl + inc - v;
    if (tid == 255) blocksums[blockIdx.x] = wexcl + inc;
}

__global__ __launch_bounds__(512) void scan2_kernel(int* __restrict__ bs, int nb) {
    const int tid = threadIdx.x, lane = tid & 63, wid = tid >> 6;
    int v = (tid < nb) ? bs[tid] : 0;
    int inc = wave_incl_scan(v, lane);
    __shared__ int wtot[8];
    if (lane == 63) wtot[wid] = inc;
    __syncthreads();
    int wexcl = 0;
#pragma unroll
    for (int w = 0; w < 8; ++w)
        if (w < wid) wexcl += wtot[w];
    if (tid < nb) bs[tid] = wexcl + inc - v;
}

__global__ __launch_bounds__(256) void scan3_kernel(
    int* __restrict__ offsets, const int* __restrict__ bs,
    int* __restrict__ cursor, int* __restrict__ edata, int n, int E)
{
    const int i = blockIdx.x * 256 + threadIdx.x;
    if (i < n) {
        const int v = offsets[i] + bs[i >> 8];
        offsets[i] = v;
        cursor[i] = v;
    }
    if (i == 0) {
        offsets[n] = E;
        edata[E] = 0;   // sentinel for clamped reads on empty segments
    }
}

__global__ void scatter_kernel(const int* __restrict__ ei, const int* __restrict__ sgn,
                               int* __restrict__ cursor, int* __restrict__ edata, int E) {
    const int i = blockIdx.x * blockDim.x + threadIdx.x;
    if (i < E) {
        const int r = ei[i];
        const int c = ei[E + i];
        const int s = sgn[i];
        const int pos = atomicAdd(&cursor[r], 1);
        edata[pos] = c | (s << 20);
    }
}

// 4 nodes per wave; 16 lanes per node; lane holds float4 of the feature row.
// head = (lane&15)>>2  -> per-head dot is a 4-lane quad reduce (2 DPP ops).
__global__ __launch_bounds__(256) void attn_kernel(
    const float* __restrict__ h, const int* __restrict__ offsets,
    const int* __restrict__ edata, const float* __restrict__ sign_tab,
    float* __restrict__ aggr, int n)
{
    const int lane = threadIdx.x & 63;
    const int gl   = lane & 15;
    const int node = blockIdx.x * 16 + ((threadIdx.x >> 6) << 2) + (lane >> 4);
    const bool alive = node < n;

    int beg = 0, deg = 0;
    if (alive) {
        beg = offsets[node];
        deg = offsets[node + 1] - beg;
    }
    float4 hi = make_float4(0.f, 0.f, 0.f, 0.f);
    if (alive) hi = *reinterpret_cast<const float4*>(h + (size_t)node * DIM + gl * 4);

    const float4 s0 = *reinterpret_cast<const float4*>(sign_tab + (gl & 3) * 4);
    const float4 s1 = *reinterpret_cast<const float4*>(sign_tab + 16 + (gl & 3) * 4);
    const float4 hs0 = make_float4(hi.x * s0.x, hi.y * s0.y, hi.z * s0.z, hi.w * s0.w);
    const float4 hs1 = make_float4(hi.x * s1.x, hi.y * s1.y, hi.z * s1.z, hi.w * s1.w);

    const int degm1 = deg - 1;
    int maxdeg = max(deg, __shfl_xor(deg, 16, 64));
    maxdeg = max(maxdeg, __shfl_xor(maxdeg, 32, 64));

    float den = 0.f;
    float4 msg = make_float4(0.f, 0.f, 0.f, 0.f);

    for (int e = 0; e < maxdeg; e += 2) {
        const int i0 = max(0, min(e, degm1));
        const int i1 = max(0, min(e + 1, degm1));
        const int p0 = edata[beg + i0];
        const int p1 = edata[beg + i1];
        const int c0 = p0 & 0xFFFFF;
        const int c1 = p1 & 0xFFFFF;
        const float4 hj0 = *reinterpret_cast<const float4*>(h + (size_t)c0 * DIM + gl * 4);
        const float4 hj1 = *reinterpret_cast<const float4*>(h + (size_t)c1 * DIM + gl * 4);
        const float4 w0 = (p0 >> 20) ? hs1 : hs0;
        const float4 w1 = (p1 >> 20) ? hs1 : hs0;

        float sc0 = w0.x * hj0.x;
        sc0 = fmaf(w0.y, hj0.y, sc0);
        sc0 = fmaf(w0.z, hj0.z, sc0);
        sc0 = fmaf(w0.w, hj0.w, sc0);
        float sc1 = w1.x * hj1.x;
        sc1 = fmaf(w1.y, hj1.y, sc1);
        sc1 = fmaf(w1.z, hj1.z, sc1);
        sc1 = fmaf(w1.w, hj1.w, sc1);

        sc0 += qperm<0xB1>(sc0);   // quad_perm [1,0,3,2] : xor 1
        sc1 += qperm<0xB1>(sc1);
        sc0 += qperm<0x4E>(sc0);   // quad_perm [2,3,0,1] : xor 2
        sc1 += qperm<0x4E>(sc1);

        const float ex0 = (e < deg) ? __expf(sc0) : 0.f;
        const float ex1 = (e + 1 < deg) ? __expf(sc1) : 0.f;
        den += ex0 + ex1;
        msg.x = fmaf(ex0, hj0.x, msg.x);
        msg.y = fmaf(ex0, hj0.y, msg.y);
        msg.z = fmaf(ex0, hj0.z, msg.z);
        msg.w = fmaf(ex0, hj0.w, msg.w);
        msg.x = fmaf(ex1, hj1.x, msg.x);
        msg.y = fmaf(ex1, hj1.y, msg.y);
        msg.z = fmaf(ex1, hj1.z, msg.z);
        msg.w = fmaf(ex1, hj1.w, msg.w);
    }

    if (alive) {
        const float inv = 1.0f / (den + 1e-16f);
        float4 o = make_float4(msg.x * inv, msg.y * inv, msg.z * inv, msg.w * inv);
        *reinterpret_cast<float4*>(aggr + (size_t)node * DIM + gl * 4) = o;
    }
}

extern "C" void kernel_launch(void* const* d_in, const int* in_sizes, int n_in,
                              void* d_out, int out_size, void* d_ws, size_t ws_size,
                              hipStream_t stream) {
    const float* x        = (const float*)d_in[0];
    const int*   ei       = (const int*)d_in[1];
    const int*   esign    = (const int*)d_in[2];
    const float* Wl_w     = (const float*)d_in[3];
    const float* Wl_b     = (const float*)d_in[4];
    const float* sign_tab = (const float*)d_in[5];
    const float* Wh_w     = (const float*)d_in[6];
    const float* Wh_b     = (const float*)d_in[7];
    const float* w1       = (const float*)d_in[8];
    const float* b1       = (const float*)d_in[9];
    const float* w2       = (const float*)d_in[10];
    const float* b2       = (const float*)d_in[11];
    const float* eps      = (const float*)d_in[12];
    float* out = (float*)d_out;

    const int N = in_sizes[0] / DIM;
    const int E = in_sizes[2];

    float* h      = (float*)d_ws;
    float* aggr   = h + (size_t)N * DIM;
    int*   counts = (int*)(aggr + (size_t)N * DIM);
    int*   offs   = counts + N;
    int*   cursor = offs + (N + 1);
    int*   bsums  = cursor + N;
    int*   edata  = bsums + 1024;

    const int nb = (N + 255) / 256;

    // h = x @ Wl^T + Wl_b
    gemm64_kernel<0><<<1536, 256, 0, stream>>>(x, Wl_w, Wl_b, h, N);

    // CSR build
    zero_kernel<<<(N + 255) / 256, 256, 0, stream>>>(counts, N);
    hist_kernel<<<(E + 255) / 256, 256, 0, stream>>>(ei, counts, E);
    scan1_kernel<<<nb, 256, 0, stream>>>(counts, offs, bsums, N);
    scan2_kernel<<<1, 512, 0, stream>>>(bsums, nb);
    scan3_kernel<<<nb, 256, 0, stream>>>(offs, bsums, cursor, edata, N, E);
    scatter_kernel<<<(E + 255) / 256, 256, 0, stream>>>(ei, esign, cursor, edata, E);

    // segment softmax + aggregation: 4 nodes/wave, 16 nodes/block
    attn_kernel<<<(N + 15) / 16, 256, 0, stream>>>(h, offs, edata, sign_tab, aggr, N);

    // fused: z -> relu mlp -> out
    tail_kernel<<<512, 256, 0, stream>>>(aggr, h, Wh_w, Wh_b, w1, b1, w2, b2, eps, out, N);
}